// Round 1
// baseline (443.808 us; speedup 1.0000x reference)
//
#include <hip/hip_runtime.h>

#define TT 32      // time positions per conv block
#define CD 256     // channels (C_in == C_out == 256 for both conv layers)

// conv1d(K=3, pad=1) -> +bias -> LayerNorm(F) -> ReLU, fused.
// Block: 256 threads, thread = output channel f. Covers TT consecutive t.
__global__ __launch_bounds__(256, 2)
void conv_ln_relu_kernel(const float* __restrict__ in, const float* __restrict__ w,
                         const float* __restrict__ cbias,
                         const float* __restrict__ gamma, const float* __restrict__ beta,
                         float* __restrict__ out, int T)
{
    // smem: phase 1 = x transposed [d][row 0..33] stride 36 (36.9 KB)
    //       phase 2 = y [tt][f] stride 257 (32.9 KB, reused)
    __shared__ float smem[CD * 36];
    __shared__ float wch[24 * 257];   // weight chunk: [j = dd*3+k][f], 8 d's at a time
    __shared__ float mu_s[TT], rs_s[TT];

    const int tid  = threadIdx.x;
    const int nb_t = T / TT;
    const int b    = blockIdx.x / nb_t;
    const int t0   = (blockIdx.x % nb_t) * TT;

    // Stage x rows t0-1 .. t0+TT (34 rows), transposed: smem[d*36 + row]
    {
        const float* inb = in + (size_t)b * T * CD + tid;
        #pragma unroll 4
        for (int r = 0; r < TT + 2; ++r) {
            int t = t0 - 1 + r;
            float v = 0.f;
            if (t >= 0 && t < T) v = inb[(size_t)t * CD];
            smem[tid * 36 + r] = v;
        }
    }

    float acc[TT];
    #pragma unroll
    for (int i = 0; i < TT; ++i) acc[i] = 0.f;

    for (int dc = 0; dc < CD; dc += 8) {
        __syncthreads();   // protect wch from previous iteration's readers
        // Stage w[f=tid][dc..dc+7][0..2]: 24 contiguous floats per thread (coalesced-ish,
        // each thread streams its own row; 16B loads), write transposed to wch[j][f].
        {
            const float* wp = w + (size_t)tid * (CD * 3) + dc * 3;
            #pragma unroll
            for (int j = 0; j < 24; j += 4) {
                float4 wv = *(const float4*)(wp + j);
                wch[(j + 0) * 257 + tid] = wv.x;
                wch[(j + 1) * 257 + tid] = wv.y;
                wch[(j + 2) * 257 + tid] = wv.z;
                wch[(j + 3) * 257 + tid] = wv.w;
            }
        }
        __syncthreads();

        #pragma unroll
        for (int dd = 0; dd < 8; ++dd) {
            const float* xp = &smem[(dc + dd) * 36];
            float xv[TT + 2];
            #pragma unroll
            for (int r = 0; r < TT; r += 4) {  // broadcast b128 LDS reads
                float4 t4 = *(const float4*)(xp + r);
                xv[r] = t4.x; xv[r + 1] = t4.y; xv[r + 2] = t4.z; xv[r + 3] = t4.w;
            }
            xv[TT]     = xp[TT];
            xv[TT + 1] = xp[TT + 1];
            float w0 = wch[(dd * 3 + 0) * 257 + tid];
            float w1 = wch[(dd * 3 + 1) * 257 + tid];
            float w2 = wch[(dd * 3 + 2) * 257 + tid];
            #pragma unroll
            for (int t = 0; t < TT; ++t)
                acc[t] += w0 * xv[t] + w1 * xv[t + 1] + w2 * xv[t + 2];
        }
    }

    // conv bias
    {
        float cb = cbias[tid];
        #pragma unroll
        for (int t = 0; t < TT; ++t) acc[t] += cb;
    }

    // LayerNorm over f per position: stash y in LDS (reuse smem), segmented reduce.
    __syncthreads();               // all reads of xs/wch complete
    float* ys = smem;              // [tt][f] stride 257
    #pragma unroll
    for (int t = 0; t < TT; ++t) ys[t * 257 + tid] = acc[t];
    __syncthreads();

    {
        int tt = tid >> 3, seg = tid & 7;    // 8 lanes per position
        const float* yr = &ys[tt * 257 + seg * 32];
        float s = 0.f, ss = 0.f;
        #pragma unroll
        for (int i = 0; i < 32; ++i) {
            float v = yr[(i + seg * 4) & 31];   // stagger to dodge bank conflicts
            s += v; ss += v * v;
        }
        #pragma unroll
        for (int off = 4; off > 0; off >>= 1) {
            s  += __shfl_down(s, off, 8);
            ss += __shfl_down(ss, off, 8);
        }
        if (seg == 0) {
            float mu  = s * (1.f / 256.f);
            float var = ss * (1.f / 256.f) - mu * mu;
            mu_s[tt] = mu;
            rs_s[tt] = rsqrtf(var + 1e-5f);
        }
    }
    __syncthreads();

    {
        float gf = gamma[tid], bf = beta[tid];
        float* ob = out + ((size_t)b * T + t0) * CD + tid;
        #pragma unroll
        for (int t = 0; t < TT; ++t) {
            float v = (acc[t] - mu_s[t]) * rs_s[t] * gf + bf;
            ob[(size_t)t * CD] = fmaxf(v, 0.f);
        }
    }
}

// Per-batch inclusive scan of durations + searchsorted(right) per output frame.
__global__ void scan_idx_kernel(const int* __restrict__ target, int* __restrict__ idxbuf,
                                int T, int TOUT)
{
    __shared__ int cum[512];
    const int b = blockIdx.x, tid = threadIdx.x;
    cum[tid] = target[b * T + tid];
    __syncthreads();
    for (int off = 1; off < 512; off <<= 1) {
        int v = (tid >= off) ? cum[tid - off] : 0;
        __syncthreads();
        cum[tid] += v;
        __syncthreads();
    }
    const int total = cum[T - 1];
    for (int t = tid; t < TOUT; t += 512) {
        int lo = 0, hi = T;
        while (lo < hi) {                 // first j with cum[j] > t
            int mid = (lo + hi) >> 1;
            if (cum[mid] <= t) lo = mid + 1; else hi = mid;
        }
        idxbuf[b * TOUT + t] = (t < total) ? ((lo < T) ? lo : T - 1) : -1;
    }
}

// out[b, t_out, :] = idx >= 0 ? x[b, idx, :] : 0   (float4, fully coalesced)
__global__ __launch_bounds__(256)
void gather_kernel(const float* __restrict__ x, const int* __restrict__ idxbuf,
                   float* __restrict__ out, int T, int TOUT, int B)
{
    const size_t e  = (size_t)blockIdx.x * 256 + threadIdx.x;   // float4 index
    const size_t NE = (size_t)B * TOUT * 64;
    if (e >= NE) return;
    const int    d4  = (int)(e & 63);
    const size_t rt  = e >> 6;            // b*TOUT + t_out
    const int    idx = idxbuf[rt];        // broadcast within 64-lane group
    const int    b   = (int)(rt / TOUT);
    float4 v = make_float4(0.f, 0.f, 0.f, 0.f);
    if (idx >= 0)
        v = *(const float4*)(x + (((size_t)b * T + idx) << 8) + (d4 << 2));
    *(float4*)((float*)out + (e << 2)) = v;
}

// dur_pred[row] = relu(dot(h2[row,:], lin_w) + lin_b). One wave per row.
__global__ __launch_bounds__(256)
void dur_kernel(const float* __restrict__ h, const float* __restrict__ lw,
                const float* __restrict__ lb, float* __restrict__ dur)
{
    const int row  = blockIdx.x * 4 + (threadIdx.x >> 6);
    const int lane = threadIdx.x & 63;
    float4 hv = *(const float4*)(h + (size_t)row * 256 + lane * 4);
    float4 wv = *(const float4*)(lw + lane * 4);
    float s = hv.x * wv.x + hv.y * wv.y + hv.z * wv.z + hv.w * wv.w;
    #pragma unroll
    for (int off = 32; off > 0; off >>= 1) s += __shfl_down(s, off, 64);
    if (lane == 0) dur[row] = fmaxf(s + lb[0], 0.f);
}

extern "C" void kernel_launch(void* const* d_in, const int* in_sizes, int n_in,
                              void* d_out, int out_size, void* d_ws, size_t ws_size,
                              hipStream_t stream) {
    const float* x      = (const float*)d_in[0];
    const int*   target = (const int*)  d_in[1];
    // d_in[2] = mel_max_length (device scalar; derived from out_size instead)
    const float* c1w = (const float*)d_in[3];
    const float* c1b = (const float*)d_in[4];
    const float* g1  = (const float*)d_in[5];
    const float* b1  = (const float*)d_in[6];
    const float* c2w = (const float*)d_in[7];
    const float* c2b = (const float*)d_in[8];
    const float* g2  = (const float*)d_in[9];
    const float* b2  = (const float*)d_in[10];
    const float* lw  = (const float*)d_in[11];
    const float* lb  = (const float*)d_in[12];

    const int B = 32, T = 512, C = CD;
    const int BT = B * T;
    const int TOUT = (out_size - BT) / (B * C);   // = 2304

    // workspace: h1 (16 MB) | h2 (16 MB) | idxbuf (B*TOUT ints)
    float* h1     = (float*)d_ws;
    float* h2     = h1 + (size_t)BT * C;
    int*   idxbuf = (int*)(h2 + (size_t)BT * C);

    float* out0 = (float*)d_out;                       // [B, TOUT, C]
    float* durp = out0 + (size_t)B * TOUT * C;         // [B, T]

    conv_ln_relu_kernel<<<B * (T / TT), 256, 0, stream>>>(x,  c1w, c1b, g1, b1, h1, T);
    conv_ln_relu_kernel<<<B * (T / TT), 256, 0, stream>>>(h1, c2w, c2b, g2, b2, h2, T);
    dur_kernel<<<BT / 4, 256, 0, stream>>>(h2, lw, lb, durp);
    scan_idx_kernel<<<B, 512, 0, stream>>>(target, idxbuf, T, TOUT);
    gather_kernel<<<(int)(((size_t)B * TOUT * 64 + 255) / 256), 256, 0, stream>>>(
        x, idxbuf, out0, T, TOUT, B);
}

// Round 2
// 184.500 us; speedup vs baseline: 2.4055x; 2.4055x over previous
//
#include <hip/hip_runtime.h>

typedef __attribute__((ext_vector_type(8))) short short8;   // 8 bf16 = 4 VGPRs
typedef __attribute__((ext_vector_type(4))) float floatx4;  // MFMA acc

static __device__ __forceinline__ unsigned short f2bf(float f) {
    unsigned int u = __float_as_uint(f);
    unsigned int r = (u + 0x7FFFu + ((u >> 16) & 1u)) >> 16;   // RNE
    return (unsigned short)r;
}

// ---------- prep: x -> bf16 padded [B][514][256]; zero pad rows of xb AND h1b ----------
__global__ __launch_bounds__(256)
void prep_x_kernel(const float* __restrict__ x, ushort* __restrict__ xb,
                   ushort* __restrict__ h1b)
{
    const int r = blockIdx.x * 4 + (threadIdx.x >> 6);   // row in [0, 32*514)
    const int c = (threadIdx.x & 63) * 4;
    const int b = r / 514, tp = r % 514;
    ushort4 o;
    if (tp >= 1 && tp <= 512) {
        float4 v = *(const float4*)(x + ((size_t)(b * 512 + tp - 1) * 256 + c));
        o.x = f2bf(v.x); o.y = f2bf(v.y); o.z = f2bf(v.z); o.w = f2bf(v.w);
    } else {
        o.x = o.y = o.z = o.w = 0;
        *(ushort4*)(h1b + (size_t)r * 256 + c) = o;      // zero h1b pad rows too
    }
    *(ushort4*)(xb + (size_t)r * 256 + c) = o;
}

// ---------- prep: w[F][C][3] -> step-blocked bf16 wpb[s=0..23][n=f][kk=0..31] ----------
// GEMM K index j = k_rel*256 + c; step s = j/32, kk = j%32.
__global__ __launch_bounds__(256)
void prep_w_kernel(const float* __restrict__ w, ushort* __restrict__ wpb)
{
    const int e = blockIdx.x * 256 + threadIdx.x;        // < 196608
    const int f = e / 768, j = e % 768;
    const int c = j & 255, kr = j >> 8;
    wpb[(j >> 5) * 8192 + f * 32 + (j & 31)] = f2bf(w[f * 768 + c * 3 + kr]);
}

// ---------- fused conv1d(K=3) GEMM (bf16 MFMA) + bias + LayerNorm + ReLU ----------
// Block = 256 thr (4 waves), tile 64 rows x 256 cols, K=768 in 24 steps of 32.
// IS_CONV2: epilogue computes dur_pred = relu(relu(ln)·lw + lb) instead of storing h.
#define YS 259   // epilogue LDS row stride (floats); 259%32=3 -> conflict-free patterns
template<bool IS_CONV2>
__global__ __launch_bounds__(256)
void conv_mfma_kernel(const ushort* __restrict__ xb,   // [B][514][256] bf16 (padded)
                      const ushort* __restrict__ wpb,  // [24][256][32] bf16
                      const float* __restrict__ cbias,
                      const float* __restrict__ gamma, const float* __restrict__ beta,
                      const float* __restrict__ lw, const float* __restrict__ lb,
                      ushort* __restrict__ outb,       // conv1: h1b (padded bf16)
                      float* __restrict__ durp)        // conv2: [B][512]
{
    __shared__ __align__(16) float smem[64 * YS];      // 66.3 KB, aliased: staging | ys
    __shared__ float mu_s[64], rs_s[64];
    short* Asm = (short*)smem;                          // [64][40] bf16 (80 B rows)
    short* Bsm = Asm + 64 * 40;                         // [256][40] bf16

    const int tid  = threadIdx.x;
    const int w    = tid >> 6, lane = tid & 63;
    const int q    = lane >> 4, col = lane & 15;
    const int b    = blockIdx.x >> 3;
    const int t0   = (blockIdx.x & 7) << 6;

    floatx4 acc[4][4] = {};

    const ushort* xrow = xb + ((size_t)b * 514 + t0) * 256;
    const int am  = tid >> 2, ao = tid & 3;             // A-fill chunk mapping

    for (int s = 0; s < 24; ++s) {
        // A tile [64][32]: row m = window row t0+m+krow, cols cb..cb+31 (contiguous)
        {
            const int krow = s >> 3, cb = (s & 7) << 5;
            short8 v = *(const short8*)(xrow + (size_t)(am + krow) * 256 + cb + ao * 8);
            *(short8*)(Asm + am * 40 + ao * 8) = v;
        }
        // B tile [256][32]: contiguous 16 KB at wpb + s*8192 (coalesced)
        {
            const ushort* wsrc = wpb + s * 8192;
            #pragma unroll
            for (int i = 0; i < 4; ++i) {
                int g = i * 256 + tid;
                short8 v = *(const short8*)(wsrc + g * 8);
                *(short8*)(Bsm + (g >> 2) * 40 + (g & 3) * 8) = v;
            }
        }
        __syncthreads();
        short8 af[4], bf8[4];
        #pragma unroll
        for (int mi = 0; mi < 4; ++mi)
            af[mi] = *(const short8*)(Asm + (mi * 16 + col) * 40 + q * 8);
        #pragma unroll
        for (int ni = 0; ni < 4; ++ni)
            bf8[ni] = *(const short8*)(Bsm + (w * 64 + ni * 16 + col) * 40 + q * 8);
        #pragma unroll
        for (int mi = 0; mi < 4; ++mi)
            #pragma unroll
            for (int ni = 0; ni < 4; ++ni)
                acc[mi][ni] = __builtin_amdgcn_mfma_f32_16x16x32_bf16(
                    af[mi], bf8[ni], acc[mi][ni], 0, 0, 0);
        __syncthreads();
    }

    // ---- epilogue: acc (+bias) -> ys LDS, LN stats, normalize+ReLU ----
    float cb4[4];
    #pragma unroll
    for (int ni = 0; ni < 4; ++ni) cb4[ni] = cbias[w * 64 + ni * 16 + col];
    #pragma unroll
    for (int mi = 0; mi < 4; ++mi)
        #pragma unroll
        for (int ni = 0; ni < 4; ++ni)
            #pragma unroll
            for (int r = 0; r < 4; ++r)
                smem[(mi * 16 + q * 4 + r) * YS + w * 64 + ni * 16 + col] =
                    acc[mi][ni][r] + cb4[ni];
    __syncthreads();

    {   // LN stats: 4 lanes/row, 64 elems each (staggered reads)
        const int row = tid >> 2, seg = tid & 3;
        const float* yr = smem + row * YS + seg * 64;
        float sm = 0.f, ssm = 0.f;
        #pragma unroll 8
        for (int i = 0; i < 64; ++i) {
            float v = yr[(i + seg * 16) & 63];
            sm += v; ssm += v * v;
        }
        sm  += __shfl_down(sm, 2, 4);  sm  += __shfl_down(sm, 1, 4);
        ssm += __shfl_down(ssm, 2, 4); ssm += __shfl_down(ssm, 1, 4);
        if (seg == 0) {
            float mu = sm * (1.f / 256.f);
            float var = ssm * (1.f / 256.f) - mu * mu;
            mu_s[row] = mu;
            rs_s[row] = rsqrtf(var + 1e-5f);
        }
    }
    __syncthreads();

    const float gf = gamma[tid], bt = beta[tid];
    if (!IS_CONV2) {
        ushort* dst = outb + ((size_t)b * 514 + t0 + 1) * 256 + tid;
        #pragma unroll 4
        for (int m = 0; m < 64; ++m) {
            float v = (smem[m * YS + tid] - mu_s[m]) * rs_s[m] * gf + bt;
            dst[(size_t)m * 256] = f2bf(fmaxf(v, 0.f));
        }
    } else {
        const float lwv = lw[tid];
        #pragma unroll 4
        for (int m = 0; m < 64; ++m) {
            float v = (smem[m * YS + tid] - mu_s[m]) * rs_s[m] * gf + bt;
            smem[m * YS + tid] = fmaxf(v, 0.f) * lwv;   // in-place (own column)
        }
        __syncthreads();
        const int row = tid >> 2, seg = tid & 3;
        const float* yr = smem + row * YS + seg * 64;
        float sm = 0.f;
        #pragma unroll 8
        for (int i = 0; i < 64; ++i) sm += yr[(i + seg * 16) & 63];
        sm += __shfl_down(sm, 2, 4); sm += __shfl_down(sm, 1, 4);
        if (seg == 0) durp[b * 512 + t0 + row] = fmaxf(sm + lb[0], 0.f);
    }
}

// ---------- per-batch cumsum + searchsorted(right) ----------
__global__ void scan_idx_kernel(const int* __restrict__ target, int* __restrict__ idxbuf,
                                int T, int TOUT)
{
    __shared__ int cum[512];
    const int b = blockIdx.x, tid = threadIdx.x;
    cum[tid] = target[b * T + tid];
    __syncthreads();
    for (int off = 1; off < 512; off <<= 1) {
        int v = (tid >= off) ? cum[tid - off] : 0;
        __syncthreads();
        cum[tid] += v;
        __syncthreads();
    }
    const int total = cum[T - 1];
    for (int t = tid; t < TOUT; t += 512) {
        int lo = 0, hi = T;
        while (lo < hi) {
            int mid = (lo + hi) >> 1;
            if (cum[mid] <= t) lo = mid + 1; else hi = mid;
        }
        idxbuf[b * TOUT + t] = (t < total) ? ((lo < T) ? lo : T - 1) : -1;
    }
}

// ---------- out[b,t_out,:] = idx>=0 ? x[b,idx,:] : 0 (float4 coalesced) ----------
__global__ __launch_bounds__(256)
void gather_kernel(const float* __restrict__ x, const int* __restrict__ idxbuf,
                   float* __restrict__ out, int T, int TOUT, int B)
{
    const size_t e  = (size_t)blockIdx.x * 256 + threadIdx.x;
    const size_t NE = (size_t)B * TOUT * 64;
    if (e >= NE) return;
    const int    d4  = (int)(e & 63);
    const size_t rt  = e >> 6;
    const int    idx = idxbuf[rt];
    const int    b   = (int)(rt / TOUT);
    float4 v = make_float4(0.f, 0.f, 0.f, 0.f);
    if (idx >= 0)
        v = *(const float4*)(x + (((size_t)b * T + idx) << 8) + (d4 << 2));
    *(float4*)((float*)out + (e << 2)) = v;
}

extern "C" void kernel_launch(void* const* d_in, const int* in_sizes, int n_in,
                              void* d_out, int out_size, void* d_ws, size_t ws_size,
                              hipStream_t stream) {
    const float* x      = (const float*)d_in[0];
    const int*   target = (const int*)  d_in[1];
    const float* c1w = (const float*)d_in[3];
    const float* c1b = (const float*)d_in[4];
    const float* g1  = (const float*)d_in[5];
    const float* b1  = (const float*)d_in[6];
    const float* c2w = (const float*)d_in[7];
    const float* c2b = (const float*)d_in[8];
    const float* g2  = (const float*)d_in[9];
    const float* b2  = (const float*)d_in[10];
    const float* lw  = (const float*)d_in[11];
    const float* lb  = (const float*)d_in[12];

    const int B = 32, T = 512, C = 256;
    const int BT = B * T;
    const int TOUT = (out_size - BT) / (B * C);   // 2304

    // workspace: xb | h1b (bf16 padded [B][514][256]) | w1pb | w2pb | idxbuf
    const size_t PADEL = (size_t)B * 514 * 256;   // 4,210,688
    ushort* xb    = (ushort*)d_ws;
    ushort* h1b   = xb + PADEL;
    ushort* w1pb  = h1b + PADEL;
    ushort* w2pb  = w1pb + 196608;
    int*    idxbuf = (int*)(w2pb + 196608);

    float* out0 = (float*)d_out;                  // [B, TOUT, C]
    float* durp = out0 + (size_t)B * TOUT * C;    // [B, T]

    prep_x_kernel<<<(B * 514) / 4, 256, 0, stream>>>(x, xb, h1b);
    prep_w_kernel<<<768, 256, 0, stream>>>(c1w, w1pb);
    prep_w_kernel<<<768, 256, 0, stream>>>(c2w, w2pb);

    conv_mfma_kernel<false><<<256, 256, 0, stream>>>(xb,  w1pb, c1b, g1, b1,
                                                     nullptr, nullptr, h1b, nullptr);
    conv_mfma_kernel<true ><<<256, 256, 0, stream>>>(h1b, w2pb, c2b, g2, b2,
                                                     lw, lb, nullptr, durp);

    scan_idx_kernel<<<B, 512, 0, stream>>>(target, idxbuf, T, TOUT);
    gather_kernel<<<(int)(((size_t)B * TOUT * 64 + 255) / 256), 256, 0, stream>>>(
        x, idxbuf, out0, T, TOUT, B);
}

// Round 3
// 179.228 us; speedup vs baseline: 2.4762x; 1.0294x over previous
//
#include <hip/hip_runtime.h>

typedef __attribute__((ext_vector_type(8))) short short8;   // 8 bf16 = 4 VGPRs
typedef __attribute__((ext_vector_type(4))) float floatx4;  // MFMA acc

#define TOUT_C 2304

static __device__ __forceinline__ unsigned short f2bf(float f) {
    unsigned int u = __float_as_uint(f);
    return (unsigned short)((u + 0x7FFFu + ((u >> 16) & 1u)) >> 16);   // RNE
}

// ---- merged prep: x->bf16 padded [B][514][256], w repack, per-batch scan+search ----
// blocks [0,4112): x;  [4112,4880): w1;  [4880,5648): w2;  [5648,5680): scan
__global__ __launch_bounds__(256)
void prep_kernel(const float* __restrict__ x, const float* __restrict__ w1,
                 const float* __restrict__ w2, const int* __restrict__ target,
                 ushort* __restrict__ xb, ushort* __restrict__ h1b,
                 ushort* __restrict__ w1pb, ushort* __restrict__ w2pb,
                 int* __restrict__ idxbuf)
{
    const int blk = blockIdx.x, tid = threadIdx.x;
    if (blk < 4112) {
        const int r = blk * 4 + (tid >> 6);
        const int c = (tid & 63) * 4;
        const int b = r / 514, tp = r % 514;
        ushort4 o;
        if (tp >= 1 && tp <= 512) {
            float4 v = *(const float4*)(x + ((size_t)(b * 512 + tp - 1) * 256 + c));
            o.x = f2bf(v.x); o.y = f2bf(v.y); o.z = f2bf(v.z); o.w = f2bf(v.w);
        } else {
            o.x = o.y = o.z = o.w = 0;
            *(ushort4*)(h1b + (size_t)r * 256 + c) = o;   // zero h1b pad rows
        }
        *(ushort4*)(xb + (size_t)r * 256 + c) = o;
    } else if (blk < 5648) {
        // w[F][C][3] -> wpb[s=j/32][f][j%32], GEMM K index j = k_rel*256 + c
        const bool second = blk >= 4880;
        const int e = (blk - (second ? 4880 : 4112)) * 256 + tid;
        const float* w = second ? w2 : w1;
        ushort* wpb = second ? w2pb : w1pb;
        const int f = e / 768, j = e % 768;
        const int c = j & 255, kr = j >> 8;
        wpb[(j >> 5) * 8192 + f * 32 + (j & 31)] = f2bf(w[f * 768 + c * 3 + kr]);
    } else {
        __shared__ int cum[512];
        __shared__ int ps[256];
        const int b = blk - 5648;
        const int v0 = target[b * 512 + 2 * tid];
        const int v1 = target[b * 512 + 2 * tid + 1];
        ps[tid] = v0 + v1;
        __syncthreads();
        for (int off = 1; off < 256; off <<= 1) {
            int t = (tid >= off) ? ps[tid - off] : 0;
            __syncthreads();
            ps[tid] += t;
            __syncthreads();
        }
        const int excl = tid ? ps[tid - 1] : 0;
        cum[2 * tid]     = excl + v0;
        cum[2 * tid + 1] = excl + v0 + v1;
        __syncthreads();
        const int total = cum[511];
        for (int t = tid; t < TOUT_C; t += 256) {
            int lo = 0, hi = 512;
            while (lo < hi) {
                int mid = (lo + hi) >> 1;
                if (cum[mid] <= t) lo = mid + 1; else hi = mid;
            }
            idxbuf[b * TOUT_C + t] = (t < total) ? ((lo < 512) ? lo : 511) : -1;
        }
    }
}

// ---- conv1d(K=3) as barrier-free MFMA GEMM + bias + LayerNorm + ReLU (+lin head) ----
// Grid 512 (B*16), block 256 (4 waves). Tile: 32 rows x 256 cols, K=768 in 24x32.
// All fragments loaded DIRECTLY global->VGPR (weights 384 KB + acts are L2-resident);
// no LDS, no barriers in the K-loop -> compiler software-pipelines the loads.
template<bool IS_CONV2>
__global__ __launch_bounds__(256, 2)
void conv_mfma_kernel(const ushort* __restrict__ xb,   // [B][514][256] bf16 padded
                      const ushort* __restrict__ wpb,  // [24][256][32] bf16
                      const float* __restrict__ cbias,
                      const float* __restrict__ gamma, const float* __restrict__ beta,
                      const float* __restrict__ lw, const float* __restrict__ lb,
                      ushort* __restrict__ outb,       // conv1: h1b
                      float* __restrict__ durp)        // conv2: [B][512]
{
    __shared__ float sum_s[4][32], sq_s[4][32];
    __shared__ float mu_s[32], rs_s[32];

    const int tid  = threadIdx.x;
    const int w    = tid >> 6, lane = tid & 63;
    const int q    = lane >> 4, col = lane & 15;
    const int b    = blockIdx.x >> 4;
    const int t0   = (blockIdx.x & 15) << 5;

    floatx4 acc[2][4] = {};
    const ushort* xrow = xb + ((size_t)b * 514 + t0) * 256;
    const ushort* wbase = wpb + ((size_t)w * 64 + col) * 32 + q * 8;

    #pragma unroll 4
    for (int s = 0; s < 24; ++s) {
        const int krow = s >> 3, cb = (s & 7) << 5;
        short8 af[2], bf8[4];
        #pragma unroll
        for (int mi = 0; mi < 2; ++mi)
            af[mi] = *(const short8*)(xrow + (size_t)(mi * 16 + col + krow) * 256
                                      + cb + q * 8);
        #pragma unroll
        for (int ni = 0; ni < 4; ++ni)
            bf8[ni] = *(const short8*)(wbase + (size_t)s * 8192 + ni * 512);
        #pragma unroll
        for (int mi = 0; mi < 2; ++mi)
            #pragma unroll
            for (int ni = 0; ni < 4; ++ni)
                acc[mi][ni] = __builtin_amdgcn_mfma_f32_16x16x32_bf16(
                    af[mi], bf8[ni], acc[mi][ni], 0, 0, 0);
    }

    // ---- epilogue: bias + per-row LN stats from registers ----
    const int base_c = w * 64;
    float cb4[4], gm4[4], bt4[4];
    #pragma unroll
    for (int ni = 0; ni < 4; ++ni) {
        cb4[ni] = cbias[base_c + ni * 16 + col];
        gm4[ni] = gamma[base_c + ni * 16 + col];
        bt4[ni] = beta [base_c + ni * 16 + col];
    }
    float rsum[2][4] = {}, rsq[2][4] = {};
    #pragma unroll
    for (int mi = 0; mi < 2; ++mi)
        #pragma unroll
        for (int ni = 0; ni < 4; ++ni)
            #pragma unroll
            for (int r = 0; r < 4; ++r) {
                float v = acc[mi][ni][r] + cb4[ni];
                acc[mi][ni][r] = v;
                rsum[mi][r] += v;
                rsq [mi][r] += v * v;
            }
    #pragma unroll
    for (int mi = 0; mi < 2; ++mi)
        #pragma unroll
        for (int r = 0; r < 4; ++r) {
            float s = rsum[mi][r], ss = rsq[mi][r];
            #pragma unroll
            for (int d = 8; d > 0; d >>= 1) {
                s  += __shfl_down(s,  d, 16);
                ss += __shfl_down(ss, d, 16);
            }
            if (col == 0) {
                sum_s[w][mi * 16 + q * 4 + r] = s;
                sq_s [w][mi * 16 + q * 4 + r] = ss;
            }
        }
    __syncthreads();
    if (tid < 32) {
        float s  = sum_s[0][tid] + sum_s[1][tid] + sum_s[2][tid] + sum_s[3][tid];
        float ss = sq_s [0][tid] + sq_s [1][tid] + sq_s [2][tid] + sq_s [3][tid];
        float mu = s * (1.f / 256.f);
        float var = ss * (1.f / 256.f) - mu * mu;
        mu_s[tid] = mu;
        rs_s[tid] = rsqrtf(var + 1e-5f);
    }
    __syncthreads();

    if (!IS_CONV2) {
        #pragma unroll
        for (int mi = 0; mi < 2; ++mi)
            #pragma unroll
            for (int ni = 0; ni < 4; ++ni)
                #pragma unroll
                for (int r = 0; r < 4; ++r) {
                    int row = mi * 16 + q * 4 + r;
                    float v = (acc[mi][ni][r] - mu_s[row]) * rs_s[row] * gm4[ni] + bt4[ni];
                    outb[((size_t)b * 514 + t0 + row + 1) * 256 + base_c + ni * 16 + col]
                        = f2bf(fmaxf(v, 0.f));
                }
    } else {
        float lw4[4];
        #pragma unroll
        for (int ni = 0; ni < 4; ++ni) lw4[ni] = lw[base_c + ni * 16 + col];
        float dsum[2][4] = {};
        #pragma unroll
        for (int mi = 0; mi < 2; ++mi)
            #pragma unroll
            for (int ni = 0; ni < 4; ++ni)
                #pragma unroll
                for (int r = 0; r < 4; ++r) {
                    int row = mi * 16 + q * 4 + r;
                    float v = (acc[mi][ni][r] - mu_s[row]) * rs_s[row] * gm4[ni] + bt4[ni];
                    dsum[mi][r] += fmaxf(v, 0.f) * lw4[ni];
                }
        #pragma unroll
        for (int mi = 0; mi < 2; ++mi)
            #pragma unroll
            for (int r = 0; r < 4; ++r) {
                float s = dsum[mi][r];
                #pragma unroll
                for (int d = 8; d > 0; d >>= 1) s += __shfl_down(s, d, 16);
                if (col == 0) sum_s[w][mi * 16 + q * 4 + r] = s;
            }
        __syncthreads();
        if (tid < 32)
            durp[b * 512 + t0 + tid] = fmaxf(sum_s[0][tid] + sum_s[1][tid]
                                           + sum_s[2][tid] + sum_s[3][tid] + lb[0], 0.f);
    }
}

// ---- out[b,t_out,:] = idx>=0 ? x[b,idx,:] : 0 (float4 coalesced) ----
__global__ __launch_bounds__(256)
void gather_kernel(const float* __restrict__ x, const int* __restrict__ idxbuf,
                   float* __restrict__ out, int T, int TOUT, int B)
{
    const size_t e  = (size_t)blockIdx.x * 256 + threadIdx.x;
    const size_t NE = (size_t)B * TOUT * 64;
    if (e >= NE) return;
    const int    d4  = (int)(e & 63);
    const size_t rt  = e >> 6;
    const int    idx = idxbuf[rt];
    const int    b   = (int)(rt / TOUT);
    float4 v = make_float4(0.f, 0.f, 0.f, 0.f);
    if (idx >= 0)
        v = *(const float4*)(x + (((size_t)b * T + idx) << 8) + (d4 << 2));
    *(float4*)((float*)out + (e << 2)) = v;
}

extern "C" void kernel_launch(void* const* d_in, const int* in_sizes, int n_in,
                              void* d_out, int out_size, void* d_ws, size_t ws_size,
                              hipStream_t stream) {
    const float* x      = (const float*)d_in[0];
    const int*   target = (const int*)  d_in[1];
    const float* c1w = (const float*)d_in[3];
    const float* c1b = (const float*)d_in[4];
    const float* g1  = (const float*)d_in[5];
    const float* b1  = (const float*)d_in[6];
    const float* c2w = (const float*)d_in[7];
    const float* c2b = (const float*)d_in[8];
    const float* g2  = (const float*)d_in[9];
    const float* b2  = (const float*)d_in[10];
    const float* lw  = (const float*)d_in[11];
    const float* lb  = (const float*)d_in[12];

    const int B = 32, T = 512, C = 256;
    const int BT = B * T;
    const int TOUT = (out_size - BT) / (B * C);   // 2304

    const size_t PADEL = (size_t)B * 514 * 256;
    ushort* xb     = (ushort*)d_ws;
    ushort* h1b    = xb + PADEL;
    ushort* w1pb   = h1b + PADEL;
    ushort* w2pb   = w1pb + 196608;
    int*    idxbuf = (int*)(w2pb + 196608);

    float* out0 = (float*)d_out;                  // [B, TOUT, C]
    float* durp = out0 + (size_t)B * TOUT * C;    // [B, T]

    prep_kernel<<<5680, 256, 0, stream>>>(x, c1w, c2w, target, xb, h1b, w1pb, w2pb, idxbuf);
    conv_mfma_kernel<false><<<512, 256, 0, stream>>>(xb,  w1pb, c1b, g1, b1,
                                                     nullptr, nullptr, h1b, nullptr);
    conv_mfma_kernel<true ><<<512, 256, 0, stream>>>(h1b, w2pb, c2b, g2, b2,
                                                     lw, lb, nullptr, durp);
    gather_kernel<<<(int)(((size_t)B * TOUT * 64 + 255) / 256), 256, 0, stream>>>(
        x, idxbuf, out0, T, TOUT, B);
}

// Round 4
// 148.486 us; speedup vs baseline: 2.9889x; 1.2070x over previous
//
#include <hip/hip_runtime.h>

typedef __attribute__((ext_vector_type(8))) short short8;   // 8 bf16 = 4 VGPRs
typedef __attribute__((ext_vector_type(4))) float floatx4;  // MFMA acc

typedef __attribute__((address_space(3))) unsigned int lds_u32;
typedef __attribute__((address_space(1))) const unsigned int glb_u32;

static __device__ __forceinline__ unsigned short f2bf(float f) {
    unsigned int u = __float_as_uint(f);
    return (unsigned short)((u + 0x7FFFu + ((u >> 16) & 1u)) >> 16);   // RNE
}

// async 16-B global->LDS DMA; LDS dest = wave-uniform base + lane*16
static __device__ __forceinline__ void cp16(const ushort* g, ushort* l) {
    __builtin_amdgcn_global_load_lds((glb_u32*)g, (lds_u32*)l, 16, 0, 0);
}

// ---- prep: x->bf16 padded [B][514][256]; w[F][C][3] -> swizzled [12][256][64] ----
// blocks [0,4112): x-convert;  [4112,4880): w1;  [4880,5648): w2
// wpb logical (s,n,kk): GEMM j = kr*256+c, s=j>>6, kk=j&63; physical quad
// p = (kk>>3) ^ (n&7)  (XOR swizzle so ds_read_b128 frags are ~conflict-free).
__global__ __launch_bounds__(256)
void prep_kernel(const float* __restrict__ x, const float* __restrict__ w1,
                 const float* __restrict__ w2,
                 ushort* __restrict__ xb, ushort* __restrict__ h1b,
                 ushort* __restrict__ w1pb, ushort* __restrict__ w2pb)
{
    const int blk = blockIdx.x, tid = threadIdx.x;
    if (blk < 4112) {
        const int r = blk * 4 + (tid >> 6);
        const int c = (tid & 63) * 4;
        const int b = r / 514, tp = r % 514;
        ushort4 o;
        if (tp >= 1 && tp <= 512) {
            float4 v = *(const float4*)(x + ((size_t)(b * 512 + tp - 1) * 256 + c));
            o.x = f2bf(v.x); o.y = f2bf(v.y); o.z = f2bf(v.z); o.w = f2bf(v.w);
        } else {
            o.x = o.y = o.z = o.w = 0;
            *(ushort4*)(h1b + (size_t)r * 256 + c) = o;   // zero h1b pad rows
        }
        *(ushort4*)(xb + (size_t)r * 256 + c) = o;
    } else {
        const bool second = blk >= 4880;
        const int e = (blk - (second ? 4880 : 4112)) * 256 + tid;
        const float* w = second ? w2 : w1;
        ushort* wpb = second ? w2pb : w1pb;
        const int f = e / 768, j = e % 768;
        const int c = j & 255, kr = j >> 8;
        const int s = j >> 6, kk = j & 63;
        wpb[s * 16384 + f * 64 + (((kk >> 3) ^ (f & 7)) << 3) + (kk & 7)]
            = f2bf(w[f * 768 + c * 3 + kr]);
    }
}

// ---- conv1d(K=3) MFMA GEMM, m97-style LDS staging via global_load_lds ----
// Grid: 512 conv blocks (+1152 gather blocks when IS_CONV2). Block 256 thr.
// Tile 32 rows x 256 cols; K=768 as 12 steps of BK=64 (krow const per step).
template<bool IS_CONV2>
__global__ __launch_bounds__(256, 2)
void conv_mfma_kernel(const ushort* __restrict__ xb,   // [B][514][256] bf16 padded
                      const ushort* __restrict__ wpb,  // [12][256][64] bf16 swizzled
                      const float* __restrict__ cbias,
                      const float* __restrict__ gamma, const float* __restrict__ beta,
                      const float* __restrict__ lw, const float* __restrict__ lb,
                      ushort* __restrict__ outb,       // conv1: h1b
                      float* __restrict__ durp,        // conv2: [B][512]
                      const float* __restrict__ x,     // conv2 gather path
                      const int* __restrict__ target,
                      float* __restrict__ out0)        // [B][2304][256]
{
    __shared__ ushort As[32 * 64];    // 4 KB:  32 rows x 128 B, quad-swizzled
    __shared__ ushort Bs[256 * 64];   // 32 KB: 256 rows x 128 B, quad-swizzled
    __shared__ float sum_s[4][32], sq_s[4][32], mu_s[32], rs_s[32];
    __shared__ int cum[512], ps[256], sidx[64];       // gather path only

    const int tid = threadIdx.x;

    if (IS_CONV2 && blockIdx.x >= 512) {
        // ---------- gather: 1152 blocks, 64 output rows each ----------
        const int bg = blockIdx.x - 512;
        const int b = bg / 36, t0o = (bg % 36) * 64;
        const int v0 = target[b * 512 + 2 * tid];
        const int v1 = target[b * 512 + 2 * tid + 1];
        ps[tid] = v0 + v1;
        __syncthreads();
        for (int off = 1; off < 256; off <<= 1) {
            int t = (tid >= off) ? ps[tid - off] : 0;
            __syncthreads();
            ps[tid] += t;
            __syncthreads();
        }
        const int excl = tid ? ps[tid - 1] : 0;
        cum[2 * tid]     = excl + v0;
        cum[2 * tid + 1] = excl + v0 + v1;
        __syncthreads();
        const int total = cum[511];
        if (tid < 64) {
            int t = t0o + tid;
            int lo = 0, hi = 512;
            while (lo < hi) {
                int mid = (lo + hi) >> 1;
                if (cum[mid] <= t) lo = mid + 1; else hi = mid;
            }
            sidx[tid] = (t < total) ? ((lo < 512) ? lo : 511) : -1;
        }
        __syncthreads();
        const float4* x4 = (const float4*)x;
        float4* o4 = (float4*)out0;
        const int lane6 = tid & 63, g4 = tid >> 6;
        #pragma unroll 4
        for (int rr = 0; rr < 16; ++rr) {
            int r = rr * 4 + g4;
            int idx = sidx[r];
            float4 v = make_float4(0.f, 0.f, 0.f, 0.f);
            if (idx >= 0) v = x4[((size_t)(b * 512 + idx)) * 64 + lane6];
            o4[((size_t)(b * 2304 + t0o + r)) * 64 + lane6] = v;
        }
        return;
    }

    // ---------- conv path ----------
    const int w = tid >> 6, lane = tid & 63;
    const int q = lane >> 4, col = lane & 15;
    const int b  = blockIdx.x >> 4;
    const int t0 = (blockIdx.x & 15) << 5;

    floatx4 acc[2][4] = {};
    const ushort* xbb = xb + (size_t)b * 514 * 256;
    const int arow  = tid >> 3;                         // 0..31
    const int aquad = (tid & 7) ^ (arow & 7);           // source-quad swizzle
    ushort* AsW = As + (size_t)w * 512;                 // wave-uniform LDS bases
    ushort* BsW = Bs + (size_t)w * 512;

    for (int s = 0; s < 12; ++s) {
        const int krow = s >> 2, cb = (s & 3) << 6;
        cp16(xbb + (size_t)(t0 + krow + arow) * 256 + cb + aquad * 8, AsW);
        const ushort* wsrc = wpb + (size_t)s * 16384 + w * 512 + lane * 8;
        #pragma unroll
        for (int i = 0; i < 8; ++i)
            cp16(wsrc + i * 2048, BsW + i * 2048);
        __syncthreads();

        short8 af[2][2], bf[4][2];
        #pragma unroll
        for (int mi = 0; mi < 2; ++mi)
            #pragma unroll
            for (int kh = 0; kh < 2; ++kh)
                af[mi][kh] = *(const short8*)((const char*)As
                    + (mi * 16 + col) * 128 + (((kh * 4 + q) ^ (col & 7)) * 16));
        #pragma unroll
        for (int ni = 0; ni < 4; ++ni)
            #pragma unroll
            for (int kh = 0; kh < 2; ++kh)
                bf[ni][kh] = *(const short8*)((const char*)Bs
                    + (w * 64 + ni * 16 + col) * 128 + (((kh * 4 + q) ^ (col & 7)) * 16));
        #pragma unroll
        for (int kh = 0; kh < 2; ++kh)
            #pragma unroll
            for (int mi = 0; mi < 2; ++mi)
                #pragma unroll
                for (int ni = 0; ni < 4; ++ni)
                    acc[mi][ni] = __builtin_amdgcn_mfma_f32_16x16x32_bf16(
                        af[mi][kh], bf[ni][kh], acc[mi][ni], 0, 0, 0);
        __syncthreads();
    }

    // ---- epilogue: bias + per-row LN stats from registers ----
    const int base_c = w * 64;
    float cb4[4], gm4[4], bt4[4];
    #pragma unroll
    for (int ni = 0; ni < 4; ++ni) {
        cb4[ni] = cbias[base_c + ni * 16 + col];
        gm4[ni] = gamma[base_c + ni * 16 + col];
        bt4[ni] = beta [base_c + ni * 16 + col];
    }
    float rsum[2][4] = {}, rsq[2][4] = {};
    #pragma unroll
    for (int mi = 0; mi < 2; ++mi)
        #pragma unroll
        for (int ni = 0; ni < 4; ++ni)
            #pragma unroll
            for (int r = 0; r < 4; ++r) {
                float v = acc[mi][ni][r] + cb4[ni];
                acc[mi][ni][r] = v;
                rsum[mi][r] += v;
                rsq [mi][r] += v * v;
            }
    #pragma unroll
    for (int mi = 0; mi < 2; ++mi)
        #pragma unroll
        for (int r = 0; r < 4; ++r) {
            float s = rsum[mi][r], ss = rsq[mi][r];
            #pragma unroll
            for (int d = 8; d > 0; d >>= 1) {
                s  += __shfl_down(s,  d, 16);
                ss += __shfl_down(ss, d, 16);
            }
            if (col == 0) {
                sum_s[w][mi * 16 + q * 4 + r] = s;
                sq_s [w][mi * 16 + q * 4 + r] = ss;
            }
        }
    __syncthreads();
    if (tid < 32) {
        float s  = sum_s[0][tid] + sum_s[1][tid] + sum_s[2][tid] + sum_s[3][tid];
        float ss = sq_s [0][tid] + sq_s [1][tid] + sq_s [2][tid] + sq_s [3][tid];
        float mu = s * (1.f / 256.f);
        float var = ss * (1.f / 256.f) - mu * mu;
        mu_s[tid] = mu;
        rs_s[tid] = rsqrtf(var + 1e-5f);
    }
    __syncthreads();

    if (!IS_CONV2) {
        #pragma unroll
        for (int mi = 0; mi < 2; ++mi)
            #pragma unroll
            for (int ni = 0; ni < 4; ++ni)
                #pragma unroll
                for (int r = 0; r < 4; ++r) {
                    int row = mi * 16 + q * 4 + r;
                    float v = (acc[mi][ni][r] - mu_s[row]) * rs_s[row] * gm4[ni] + bt4[ni];
                    outb[((size_t)b * 514 + t0 + row + 1) * 256 + base_c + ni * 16 + col]
                        = f2bf(fmaxf(v, 0.f));
                }
    } else {
        float lw4[4];
        #pragma unroll
        for (int ni = 0; ni < 4; ++ni) lw4[ni] = lw[base_c + ni * 16 + col];
        float dsum[2][4] = {};
        #pragma unroll
        for (int mi = 0; mi < 2; ++mi)
            #pragma unroll
            for (int ni = 0; ni < 4; ++ni)
                #pragma unroll
                for (int r = 0; r < 4; ++r) {
                    int row = mi * 16 + q * 4 + r;
                    float v = (acc[mi][ni][r] - mu_s[row]) * rs_s[row] * gm4[ni] + bt4[ni];
                    dsum[mi][r] += fmaxf(v, 0.f) * lw4[ni];
                }
        #pragma unroll
        for (int mi = 0; mi < 2; ++mi)
            #pragma unroll
            for (int r = 0; r < 4; ++r) {
                float s = dsum[mi][r];
                #pragma unroll
                for (int d = 8; d > 0; d >>= 1) s += __shfl_down(s, d, 16);
                if (col == 0) sum_s[w][mi * 16 + q * 4 + r] = s;
            }
        __syncthreads();
        if (tid < 32)
            durp[b * 512 + t0 + tid] = fmaxf(sum_s[0][tid] + sum_s[1][tid]
                                           + sum_s[2][tid] + sum_s[3][tid] + lb[0], 0.f);
    }
}

extern "C" void kernel_launch(void* const* d_in, const int* in_sizes, int n_in,
                              void* d_out, int out_size, void* d_ws, size_t ws_size,
                              hipStream_t stream) {
    const float* x      = (const float*)d_in[0];
    const int*   target = (const int*)  d_in[1];
    const float* c1w = (const float*)d_in[3];
    const float* c1b = (const float*)d_in[4];
    const float* g1  = (const float*)d_in[5];
    const float* b1  = (const float*)d_in[6];
    const float* c2w = (const float*)d_in[7];
    const float* c2b = (const float*)d_in[8];
    const float* g2  = (const float*)d_in[9];
    const float* b2  = (const float*)d_in[10];
    const float* lw  = (const float*)d_in[11];
    const float* lb  = (const float*)d_in[12];

    const int B = 32, C = 256;

    const size_t PADEL = (size_t)B * 514 * 256;
    ushort* xb   = (ushort*)d_ws;
    ushort* h1b  = xb + PADEL;
    ushort* w1pb = h1b + PADEL;
    ushort* w2pb = w1pb + 196608;

    float* out0 = (float*)d_out;                  // [B, 2304, C]
    float* durp = out0 + (size_t)B * 2304 * C;    // [B, 512]

    prep_kernel<<<5648, 256, 0, stream>>>(x, c1w, c2w, xb, h1b, w1pb, w2pb);
    conv_mfma_kernel<false><<<512, 256, 0, stream>>>(
        xb, w1pb, c1b, g1, b1, nullptr, nullptr, h1b, nullptr,
        nullptr, nullptr, nullptr);
    conv_mfma_kernel<true><<<512 + 1152, 256, 0, stream>>>(
        h1b, w2pb, c2b, g2, b2, lw, lb, nullptr, durp,
        x, target, out0);
}